// Round 1
// baseline (248.055 us; speedup 1.0000x reference)
//
#include <hip/hip_runtime.h>
#include <math.h>

#define KS 3
#define NPT 9          // kernel points
#define H 128
#define W 128
#define C 64
#define BATCH 2
#define PIX 16         // pixels per block (one row segment)

// LDS layout (floats), total 11936 floats = 47.7 KB:
//  [0,9280)      s_val[16][580]  (aliases s_x[64][3][18]=3456 during phases 0-1)
//  [9280,9568)   s_off[16][18]
//  [9568,9616)   s_adb[16][3]
//  [9616,9760)   s_mraw[16][9]
//  [9760,10336)  s_g[16][9][4]
//  [10336,10912) s_idx[16][9][4] (int)
//  [10912,11936) s_out[64][16]

__global__ __launch_bounds__(256) void deform_kernel(
    const float* __restrict__ x, const float* __restrict__ w_p,
    const float* __restrict__ b_p, const float* __restrict__ w_m,
    const float* __restrict__ w_ad, const float* __restrict__ w_conv,
    float* __restrict__ out)
{
    __shared__ __align__(16) float smem[11936];
    float* s_val  = smem;              // [16][580]
    float* s_x    = smem;              // [64][3][18] (phase 0/1 only)
    float* s_off  = smem + 9280;       // [16][18]
    float* s_adb  = s_off + 288;       // [16][3]
    float* s_mraw = s_adb + 48;        // [16][9]
    float* s_g    = s_mraw + 144;      // [16][9][4]
    int*   s_idx  = (int*)(s_g + 576); // [16][9][4]
    float* s_out  = s_g + 1152;        // [64][16]

    const int t  = threadIdx.x;
    const int blk = blockIdx.x;
    const int jb = blk % (W / PIX);
    const int i  = (blk / (W / PIX)) % H;
    const int b  = blk / ((W / PIX) * H);
    const int j0 = jb * PIX;

    // ---- Phase 0: stage x tile rows i-1..i+1, cols j0-1..j0+16, all 64 ci ----
    for (int f = t; f < 64 * 3 * 18; f += 256) {
        int ci = f / 54; int rem = f % 54; int r = rem / 18; int c = rem % 18;
        int gi = i - 1 + r; int gj = j0 - 1 + c;
        float v = 0.f;
        if ((unsigned)gi < (unsigned)H && (unsigned)gj < (unsigned)W)
            v = x[((b * C + ci) * H + gi) * W + gj];
        s_x[f] = v;
    }
    __syncthreads();

    // ---- Phase 1: 30-channel meta conv (18 offset, 3 adaptive, 9 modulation) ----
    for (int task = t; task < 30 * PIX; task += 256) {
        int oc = task >> 4; int pix = task & 15;
        const float* wbase; float acc;
        if (oc < 18)      { wbase = w_p  + oc * 576;        acc = b_p[oc]; }
        else if (oc < 21) { wbase = w_ad + (oc - 18) * 576; acc = 0.f; }
        else              { wbase = w_m  + (oc - 21) * 576; acc = 0.f; }
        for (int ci = 0; ci < 64; ++ci) {
            const float* xb = s_x + ci * 54 + pix;
            const float* wb = wbase + ci * 9;
            #pragma unroll
            for (int r = 0; r < 3; ++r)
                #pragma unroll
                for (int c = 0; c < 3; ++c)
                    acc = fmaf(wb[r * 3 + c], xb[r * 18 + c], acc);
        }
        if (oc < 18)      s_off[pix * 18 + oc] = acc;
        else if (oc < 21) s_adb[pix * 3 + (oc - 18)] = 1.f - 1.f / (1.f + expf(-acc));
        else              s_mraw[pix * 9 + (oc - 21)] = acc;
    }
    __syncthreads();

    // ---- Phase 2: sampling corners + premultiplied bilinear weights ----
    if (t < PIX * NPT) {
        int pix = t / 9; int n = t % 9;
        int ki = n / 3, kj = n % 3;
        float adb  = s_adb[pix * 3 + kj];      // channel n % 3 == kj
        float offx = s_off[pix * 18 + n];
        float offy = s_off[pix * 18 + 9 + n];
        float pnx = (float)(ki - 1), pny = (float)(kj - 1);
        float px = (float)(i + 1)        + pnx + offx + 2.f * adb * pnx;
        float py = (float)(j0 + pix + 1) + pny + offy + 2.f * adb * pny;

        float flx = floorf(px), fly = floorf(py);
        int ix0 = (int)fminf(fmaxf(flx,       0.f), 129.f);
        int ix1 = (int)fminf(fmaxf(flx + 1.f, 0.f), 129.f);
        int iy0 = (int)fminf(fmaxf(fly,       0.f), 129.f);
        int iy1 = (int)fminf(fmaxf(fly + 1.f, 0.f), 129.f);

        // mask: snap out-of-range coords to floor, then clamp
        float ptx = (px < 1.f || px > 128.f) ? flx : px;
        float pty = (py < 1.f || py > 128.f) ? fly : py;
        ptx = fminf(fmaxf(ptx, 0.f), 129.f);
        pty = fminf(fmaxf(pty, 0.f), 129.f);

        float wxl = 1.f + (float)ix0 - ptx;
        float wxr = 1.f - ((float)ix1 - ptx);
        float wyl = 1.f + (float)iy0 - pty;
        float wyr = 1.f - ((float)iy1 - pty);

        float mraw = s_mraw[pix * 9 + n];
        float mm = (1.f / (1.f + expf(-mraw))) * (adb - 0.5f) * 4.f;

        int base = (pix * 9 + n) * 4;
        s_g[base + 0] = wxl * wyl * mm;   // lt  (ix0, iy0)
        s_g[base + 1] = wxr * wyr * mm;   // rb  (ix1, iy1)
        s_g[base + 2] = wxl * wyr * mm;   // lb  (ix0, iy1)
        s_g[base + 3] = wxr * wyl * mm;   // rt  (ix1, iy0)
        s_idx[base + 0] = ix0; s_idx[base + 1] = ix1;
        s_idx[base + 2] = iy0; s_idx[base + 3] = iy1;
    }
    __syncthreads();

    // ---- Phase 3: bilinear gathers -> s_val[pix][ci*9+n] ----
    const float* xb0 = x + (size_t)b * C * H * W;
    for (int task = t; task < PIX * 64 * 9; task += 256) {
        int pix = task & 15; int rest = task >> 4;   // rest = ci*9 + n
        int ci = rest / 9; int n = rest - ci * 9;
        int base = (pix * 9 + n) * 4;
        int ix0 = s_idx[base + 0], ix1 = s_idx[base + 1];
        int iy0 = s_idx[base + 2], iy1 = s_idx[base + 3];
        float g0 = s_g[base + 0], g1 = s_g[base + 1];
        float g2 = s_g[base + 2], g3 = s_g[base + 3];
        const float* xc = xb0 + ci * H * W;
        bool bx0 = (ix0 >= 1 && ix0 <= 128), bx1 = (ix1 >= 1 && ix1 <= 128);
        bool by0 = (iy0 >= 1 && iy0 <= 128), by1 = (iy1 >= 1 && iy1 <= 128);
        float v00 = (bx0 && by0) ? xc[(ix0 - 1) * W + iy0 - 1] : 0.f;
        float v11 = (bx1 && by1) ? xc[(ix1 - 1) * W + iy1 - 1] : 0.f;
        float v01 = (bx0 && by1) ? xc[(ix0 - 1) * W + iy1 - 1] : 0.f;
        float v10 = (bx1 && by0) ? xc[(ix1 - 1) * W + iy0 - 1] : 0.f;
        s_val[pix * 580 + rest] = g0 * v00 + g1 * v11 + g2 * v01 + g3 * v10;
    }
    __syncthreads();

    // ---- Phase 4: contraction out[pix][co] = sum_k w_conv[co][k] * val[pix][k] ----
    {
        int wv = t >> 6, l = t & 63;
        int pix = l & 15, cg = l >> 4;
        int co0 = wv * 16 + cg * 4;
        float acc0 = 0.f, acc1 = 0.f, acc2 = 0.f, acc3 = 0.f;
        const float4* wc0 = (const float4*)(w_conv + (co0 + 0) * 576);
        const float4* wc1 = (const float4*)(w_conv + (co0 + 1) * 576);
        const float4* wc2 = (const float4*)(w_conv + (co0 + 2) * 576);
        const float4* wc3 = (const float4*)(w_conv + (co0 + 3) * 576);
        const float* vb = s_val + pix * 580;
        for (int kg = 0; kg < 144; ++kg) {
            float4 v = *(const float4*)&vb[kg * 4];
            float4 a0 = wc0[kg];
            acc0 = fmaf(a0.x, v.x, fmaf(a0.y, v.y, fmaf(a0.z, v.z, fmaf(a0.w, v.w, acc0))));
            float4 a1 = wc1[kg];
            acc1 = fmaf(a1.x, v.x, fmaf(a1.y, v.y, fmaf(a1.z, v.z, fmaf(a1.w, v.w, acc1))));
            float4 a2 = wc2[kg];
            acc2 = fmaf(a2.x, v.x, fmaf(a2.y, v.y, fmaf(a2.z, v.z, fmaf(a2.w, v.w, acc2))));
            float4 a3 = wc3[kg];
            acc3 = fmaf(a3.x, v.x, fmaf(a3.y, v.y, fmaf(a3.z, v.z, fmaf(a3.w, v.w, acc3))));
        }
        s_out[(co0 + 0) * 16 + pix] = acc0;
        s_out[(co0 + 1) * 16 + pix] = acc1;
        s_out[(co0 + 2) * 16 + pix] = acc2;
        s_out[(co0 + 3) * 16 + pix] = acc3;
    }
    __syncthreads();

    // ---- Phase 5: coalesced float4 output ----
    {
        int co = t >> 2, q = t & 3;
        float4 v = *(float4*)&s_out[co * 16 + q * 4];
        *(float4*)&out[(((size_t)b * C + co) * H + i) * W + j0 + q * 4] = v;
    }
}

extern "C" void kernel_launch(void* const* d_in, const int* in_sizes, int n_in,
                              void* d_out, int out_size, void* d_ws, size_t ws_size,
                              hipStream_t stream) {
    const float* x      = (const float*)d_in[0];
    const float* w_p    = (const float*)d_in[1];
    const float* b_p    = (const float*)d_in[2];
    const float* w_m    = (const float*)d_in[3];
    const float* w_ad   = (const float*)d_in[4];
    const float* w_conv = (const float*)d_in[5];
    float* outp = (float*)d_out;

    dim3 grid(BATCH * H * (W / PIX));
    deform_kernel<<<grid, 256, 0, stream>>>(x, w_p, b_p, w_m, w_ad, w_conv, outp);
}

// Round 2
// 122.981 us; speedup vs baseline: 2.0170x; 2.0170x over previous
//
#include <hip/hip_runtime.h>
#include <math.h>

#define KS 3
#define NPT 9
#define H 128
#define W 128
#define C 64
#define BATCH 2
#define PIX 16

typedef short short8 __attribute__((ext_vector_type(8)));
typedef float f32x4 __attribute__((ext_vector_type(4)));

__device__ __forceinline__ unsigned short f2bf(float f) {
    union { float f; unsigned u; } v; v.f = f;
    unsigned r = (v.u + 0x7FFFu + ((v.u >> 16) & 1u)) >> 16;
    return (unsigned short)r;
}

// Pre-kernel: convert w_conv (64x576 fp32) to bf16 in d_ws.
__global__ __launch_bounds__(256) void cvt_wconv(const float* __restrict__ w,
                                                 unsigned short* __restrict__ o) {
    int idx = (blockIdx.x * 256 + threadIdx.x) * 4;
    float4 v = *(const float4*)(w + idx);
    ushort4 r;
    r.x = f2bf(v.x); r.y = f2bf(v.y); r.z = f2bf(v.z); r.w = f2bf(v.w);
    *(ushort4*)(o + idx) = r;
}

// LDS layout (floats), total 13356 fl = 53424 B (3 blocks/CU):
//  [0,3456)        s_x[64][3][18]
//  [3456,12156)    s_wm[15][580]          (phase 1; aliased by s_valb bf16[16][584] in phases 3-4)
//  [12156,12444)   s_off[16][18]
//  [12444,12492)   s_adb[16][3]
//  [12492,12636)   s_mraw[16][9]
//  [12636,13212)   s_g[16][9][4]
//  [13212,13356)   s_idxp[16][9] (packed int)

__global__ __launch_bounds__(256) void deform_kernel(
    const float* __restrict__ x, const float* __restrict__ w_p,
    const float* __restrict__ b_p, const float* __restrict__ w_m,
    const float* __restrict__ w_ad, const unsigned short* __restrict__ wb16,
    float* __restrict__ out)
{
    __shared__ __align__(16) float smem[13356];
    float* s_x    = smem;
    float* s_wm   = smem + 3456;
    float* s_off  = smem + 12156;
    float* s_adb  = smem + 12444;
    float* s_mraw = smem + 12492;
    float* s_g    = smem + 12636;
    int*   s_idxp = (int*)(smem + 13212);
    unsigned short* s_valb = (unsigned short*)(smem + 3456);   // [16][584] bf16

    const int t   = threadIdx.x;
    const int blk = blockIdx.x;
    const int jb = blk % (W / PIX);
    const int i  = (blk / (W / PIX)) % H;
    const int b  = blk / ((W / PIX) * H);
    const int j0 = jb * PIX;

    // ---- Phase 0: stage x tile rows i-1..i+1, cols j0-1..j0+16, all 64 ci ----
    for (int f = t; f < 64 * 3 * 18; f += 256) {
        int ci = f / 54; int rem = f % 54; int r = rem / 18; int c = rem % 18;
        int gi = i - 1 + r; int gj = j0 - 1 + c;
        float v = 0.f;
        if ((unsigned)gi < (unsigned)H && (unsigned)gj < (unsigned)W)
            v = x[((b * C + ci) * H + gi) * W + gj];
        s_x[f] = v;
    }

    // ---- Phase 1: meta conv (30 oc) in 2 chunks of 15, weights staged in LDS ----
    for (int chunk = 0; chunk < 2; ++chunk) {
        __syncthreads();   // protects s_wm (and phase-0 s_x on first iter)
        for (int f = t; f < 15 * 144; f += 256) {
            int ocl = f / 144, k4 = (f % 144) * 4;
            int oc = chunk * 15 + ocl;
            const float* src;
            if (oc < 18)      src = w_p  + oc * 576;
            else if (oc < 21) src = w_ad + (oc - 18) * 576;
            else              src = w_m  + (oc - 21) * 576;
            *(float4*)(s_wm + ocl * 580 + k4) = *(const float4*)(src + k4);
        }
        __syncthreads();
        if (t < 240) {
            int ocl = t >> 4, pix = t & 15;
            int oc = chunk * 15 + ocl;
            float acc = (oc < 18) ? b_p[oc] : 0.f;
            const float* wb = s_wm + ocl * 580;
            const float* xb = s_x + pix;
            #pragma unroll 4
            for (int ci = 0; ci < 64; ++ci) {
                const float* wp = wb + ci * 9;
                const float* xp = xb + ci * 54;
                #pragma unroll
                for (int r = 0; r < 3; ++r)
                    #pragma unroll
                    for (int c2 = 0; c2 < 3; ++c2)
                        acc = fmaf(wp[r * 3 + c2], xp[r * 18 + c2], acc);
            }
            if (oc < 18)      s_off[pix * 18 + oc] = acc;
            else if (oc < 21) s_adb[pix * 3 + (oc - 18)] = 1.f - 1.f / (1.f + expf(-acc));
            else              s_mraw[pix * 9 + (oc - 21)] = acc;
        }
    }
    __syncthreads();

    // ---- Phase 2: sampling corners + premultiplied bilinear*modulation weights ----
    if (t < PIX * NPT) {
        int pix = t / 9; int n = t % 9;
        int ki = n / 3, kj = n % 3;
        float adb  = s_adb[pix * 3 + kj];
        float offx = s_off[pix * 18 + n];
        float offy = s_off[pix * 18 + 9 + n];
        float pnx = (float)(ki - 1), pny = (float)(kj - 1);
        float px = (float)(i + 1)        + pnx + offx + 2.f * adb * pnx;
        float py = (float)(j0 + pix + 1) + pny + offy + 2.f * adb * pny;

        float flx = floorf(px), fly = floorf(py);
        int ix0 = (int)fminf(fmaxf(flx,       0.f), 129.f);
        int ix1 = (int)fminf(fmaxf(flx + 1.f, 0.f), 129.f);
        int iy0 = (int)fminf(fmaxf(fly,       0.f), 129.f);
        int iy1 = (int)fminf(fmaxf(fly + 1.f, 0.f), 129.f);

        float ptx = (px < 1.f || px > 128.f) ? flx : px;
        float pty = (py < 1.f || py > 128.f) ? fly : py;
        ptx = fminf(fmaxf(ptx, 0.f), 129.f);
        pty = fminf(fmaxf(pty, 0.f), 129.f);

        float wxl = 1.f + (float)ix0 - ptx;
        float wxr = 1.f - ((float)ix1 - ptx);
        float wyl = 1.f + (float)iy0 - pty;
        float wyr = 1.f - ((float)iy1 - pty);

        float mraw = s_mraw[pix * 9 + n];
        float mm = (1.f / (1.f + expf(-mraw))) * (adb - 0.5f) * 4.f;

        int base = (pix * 9 + n) * 4;
        s_g[base + 0] = wxl * wyl * mm;
        s_g[base + 1] = wxr * wyr * mm;
        s_g[base + 2] = wxl * wyr * mm;
        s_g[base + 3] = wxr * wyl * mm;
        s_idxp[pix * 9 + n] = ix0 | (ix1 << 8) | (iy0 << 16) | (iy1 << 24);
    }
    __syncthreads();

    // ---- Phase 3: bilinear gathers -> s_valb[pix][ci*9+n] (bf16) ----
    const float* xb0 = x + (size_t)b * C * H * W;
    for (int task = t; task < PIX * 576; task += 256) {
        int pix = task & 15; int rest = task >> 4;   // rest = ci*9 + n
        int ci = rest / 9; int n = rest - ci * 9;
        int pk = s_idxp[pix * 9 + n];
        int ix0 = pk & 255, ix1 = (pk >> 8) & 255;
        int iy0 = (pk >> 16) & 255, iy1 = (pk >> 24) & 255;
        int base = (pix * 9 + n) * 4;
        float g0 = s_g[base + 0], g1 = s_g[base + 1];
        float g2 = s_g[base + 2], g3 = s_g[base + 3];
        const float* xc = xb0 + ci * H * W;
        bool bx0 = (ix0 >= 1 && ix0 <= 128), bx1 = (ix1 >= 1 && ix1 <= 128);
        bool by0 = (iy0 >= 1 && iy0 <= 128), by1 = (iy1 >= 1 && iy1 <= 128);
        float v00 = (bx0 && by0) ? xc[(ix0 - 1) * W + iy0 - 1] : 0.f;
        float v11 = (bx1 && by1) ? xc[(ix1 - 1) * W + iy1 - 1] : 0.f;
        float v01 = (bx0 && by1) ? xc[(ix0 - 1) * W + iy1 - 1] : 0.f;
        float v10 = (bx1 && by0) ? xc[(ix1 - 1) * W + iy0 - 1] : 0.f;
        s_valb[pix * 584 + rest] = f2bf(g0 * v00 + g1 * v11 + g2 * v01 + g3 * v10);
    }
    __syncthreads();

    // ---- Phase 4: MFMA contraction out[co][pix] = sum_k wb16[co][k] * val[k][pix] ----
    {
        int wv = t >> 6, l = t & 63;
        int lr = l & 15, lg = l >> 4;
        // A: rows = co (wave tile), 8 consecutive k per lane
        const unsigned short* wa = wb16 + (wv * 16 + lr) * 576 + lg * 8;
        // B: col = pix (lr), 8 consecutive k per lane; row stride 584 bf16 = 1168 B
        const char* vbase = (const char*)s_valb + lr * 1168 + lg * 16;
        f32x4 acc = {0.f, 0.f, 0.f, 0.f};
        #pragma unroll 6
        for (int kk = 0; kk < 18; ++kk) {
            short8 a  = *(const short8*)(wa + kk * 32);
            short8 bf = *(const short8*)(vbase + kk * 64);
            acc = __builtin_amdgcn_mfma_f32_16x16x32_bf16(a, bf, acc, 0, 0, 0);
        }
        #pragma unroll
        for (int r = 0; r < 4; ++r)
            out[(((size_t)b * C + wv * 16 + lg * 4 + r) * H + i) * W + j0 + lr] = acc[r];
    }
}

extern "C" void kernel_launch(void* const* d_in, const int* in_sizes, int n_in,
                              void* d_out, int out_size, void* d_ws, size_t ws_size,
                              hipStream_t stream) {
    const float* x      = (const float*)d_in[0];
    const float* w_p    = (const float*)d_in[1];
    const float* b_p    = (const float*)d_in[2];
    const float* w_m    = (const float*)d_in[3];
    const float* w_ad   = (const float*)d_in[4];
    const float* w_conv = (const float*)d_in[5];
    float* outp = (float*)d_out;
    unsigned short* ws16 = (unsigned short*)d_ws;

    cvt_wconv<<<36, 256, 0, stream>>>(w_conv, ws16);   // 36*256*4 = 36864 = 64*576
    dim3 grid(BATCH * H * (W / PIX));
    deform_kernel<<<grid, 256, 0, stream>>>(x, w_p, b_p, w_m, w_ad, ws16, outp);
}

// Round 3
// 78.956 us; speedup vs baseline: 3.1417x; 1.5576x over previous
//
#include <hip/hip_runtime.h>
#include <math.h>

#define H 128
#define W 128
#define C 64
#define BATCH 2
#define PIX 16

typedef short short8 __attribute__((ext_vector_type(8)));
typedef float f32x4 __attribute__((ext_vector_type(4)));

// ws layout (ushort units): xT bf16 NHWC [2][128][128][64] at 0 (2097152),
// wc16 [64][576] (k-order n*64+ci) at 2097152, wmeta 3 planes [32][576] at 2134016.
#define WC_OFF 2097152
#define WM_OFF 2134016
#define WM_PLANE 18432

__device__ __forceinline__ unsigned f2bf_u(float f) {   // RNE bf16 in low 16 bits
    union { float f; unsigned u; } v; v.f = f;
    return (v.u + 0x7FFFu + ((v.u >> 16) & 1u)) >> 16;
}
__device__ __forceinline__ float bfbits2f(unsigned lo16) {
    union { unsigned u; float f; } v; v.u = lo16 << 16;
    return v.f;
}
__device__ __forceinline__ float bfhi2f(unsigned u) {
    union { unsigned u2; float f; } v; v.u2 = u & 0xFFFF0000u;
    return v.f;
}
__device__ __forceinline__ float bflo2f(unsigned u) {
    union { unsigned u2; float f; } v; v.u2 = u << 16;
    return v.f;
}
// exact 3-way bf16 split: v == h + m + l (Dekker, RNE)
__device__ __forceinline__ void split3(float v, unsigned& h, unsigned& m, unsigned& l) {
    h = f2bf_u(v);
    float r1 = v - bfbits2f(h);
    m = f2bf_u(r1);
    float r2 = r1 - bfbits2f(m);
    l = f2bf_u(r2);
}

__global__ __launch_bounds__(256) void prep_kernel(
    const float* __restrict__ x, const float* __restrict__ w_p,
    const float* __restrict__ w_m, const float* __restrict__ w_ad,
    const float* __restrict__ w_conv, unsigned short* __restrict__ ws)
{
    const int blk = blockIdx.x, t = threadIdx.x;
    if (blk < 256) {
        // transpose x NCHW fp32 -> xT NHWC bf16
        __shared__ float s[64 * 129];
        int b = blk >> 7, h = blk & 127;
        for (int f = t; f < 64 * 128; f += 256) {
            int ci = f >> 7, w = f & 127;
            s[ci * 129 + w] = x[((b * 64 + ci) * 128 + h) * 128 + w];
        }
        __syncthreads();
        unsigned* outp = (unsigned*)ws + ((size_t)(b * 128 + h) * 128) * 32;
        for (int f = t; f < 64 * 128 / 2; f += 256) {
            int w = f >> 5, cip = f & 31;
            unsigned lo = f2bf_u(s[(2 * cip) * 129 + w]);
            unsigned hi = f2bf_u(s[(2 * cip + 1) * 129 + w]);
            outp[w * 32 + cip] = lo | (hi << 16);
        }
    } else if (blk < 292) {
        // w_conv reorder to k = n*64 + ci, bf16
        int q = (blk - 256) * 256 + t;           // 0..9215
        int co = q / 144, rem = q % 144, n = rem >> 4, cig = rem & 15;
        const float* src = w_conv + co * 576;
        ushort4 r;
        r.x = (unsigned short)f2bf_u(src[(cig * 4 + 0) * 9 + n]);
        r.y = (unsigned short)f2bf_u(src[(cig * 4 + 1) * 9 + n]);
        r.z = (unsigned short)f2bf_u(src[(cig * 4 + 2) * 9 + n]);
        r.w = (unsigned short)f2bf_u(src[(cig * 4 + 3) * 9 + n]);
        *(ushort4*)(ws + WC_OFF + co * 576 + n * 64 + cig * 4) = r;
    } else {
        // meta weights: 3-way split, rows 30/31 zero-padded
        int q = (blk - 292) * 256 + t;           // 0..18431
        int oc = q / 576, k = q % 576;
        float v = 0.f;
        if (oc < 18)      v = w_p[oc * 576 + k];
        else if (oc < 21) v = w_ad[(oc - 18) * 576 + k];
        else if (oc < 30) v = w_m[(oc - 21) * 576 + k];
        unsigned h, m, l; split3(v, h, m, l);
        ws[WM_OFF + q] = (unsigned short)h;
        ws[WM_OFF + WM_PLANE + q] = (unsigned short)m;
        ws[WM_OFF + 2 * WM_PLANE + q] = (unsigned short)l;
    }
}

// LDS (floats, 9328 = 37312 B -> 4 blocks/CU):
//  [0,7104)      B planes: 3 x bf16[16][296] (im2col hi/mid/lo); later aliased by
//                s_valb bf16[16][584]
//  [7104,8128)   s_part[4][64][4] f32
//  [8128,8416)   s_off[16][18]
//  [8416,8464)   s_adb[16][3]
//  [8464,8608)   s_mraw[16][9]
//  [8608,9184)   s_g[16][9][4]
//  [9184,9328)   s_idxp[16][9]

__global__ __launch_bounds__(256, 4) void deform_kernel(
    const float* __restrict__ x, const float* __restrict__ b_p,
    const unsigned short* __restrict__ ws, float* __restrict__ out)
{
    __shared__ __align__(16) float smem[9328];
    unsigned short* Bh = (unsigned short*)smem;      // planes at +0, +4736, +9472 (ushorts)
    float* s_part = smem + 7104;
    float* s_off  = smem + 8128;
    float* s_adb  = smem + 8416;
    float* s_mraw = smem + 8464;
    float* s_g    = smem + 8608;
    int*   s_idxp = (int*)(smem + 9184);
    unsigned short* s_valb = (unsigned short*)smem;  // [16][584]

    const unsigned short* xT   = ws;
    const unsigned short* wc16 = ws + WC_OFF;
    const unsigned short* wmet = ws + WM_OFF;

    const int t   = threadIdx.x;
    const int blk = blockIdx.x;
    const int jb = blk % (W / PIX);
    const int i  = (blk / (W / PIX)) % H;
    const int b  = blk / ((W / PIX) * H);
    const int j0 = jb * PIX;

    const int wv = t >> 6, lane = t & 63, lr = lane & 15, lg = lane >> 4;
    const int tile = wv & 1, kq = wv >> 1;

    // ---- Phase 1: meta conv as 6-pass split-bf16 MFMA, K in 2 halves of 288 ----
    f32x4 acc1 = {0.f, 0.f, 0.f, 0.f};
    for (int kh = 0; kh < 2; ++kh) {
        // build im2col B for this K-half, straight from global x
        for (int it = 0; it < 5; ++it) {
            int task = t + it * 256;
            if (task < 1152) {
                int pix = task & 15, k4 = (task >> 4) * 4;
                unsigned hh[4], mh[4], lh[4];
                #pragma unroll
                for (int j = 0; j < 4; ++j) {
                    int k = kh * 288 + k4 + j;
                    int ci = k / 9, rc = k % 9, r = rc / 3, c2 = rc % 3;
                    int gi = i - 1 + r, gj = j0 - 1 + pix + c2;
                    float v = 0.f;
                    if ((unsigned)gi < 128u && (unsigned)gj < 128u)
                        v = x[((b * 64 + ci) * 128 + gi) * 128 + gj];
                    split3(v, hh[j], mh[j], lh[j]);
                }
                int bo = pix * 296 + k4;
                *(uint2*)(Bh + bo)        = make_uint2(hh[0] | (hh[1] << 16), hh[2] | (hh[3] << 16));
                *(uint2*)(Bh + 4736 + bo) = make_uint2(mh[0] | (mh[1] << 16), mh[2] | (mh[3] << 16));
                *(uint2*)(Bh + 9472 + bo) = make_uint2(lh[0] | (lh[1] << 16), lh[2] | (lh[3] << 16));
            }
        }
        __syncthreads();
        int s0 = kq ? 5 : 0, s1 = kq ? 9 : 5;
        for (int s = s0; s < s1; ++s) {
            int kk = s * 32;
            const unsigned short* wa = wmet + (tile * 16 + lr) * 576 + kh * 288 + kk + lg * 8;
            short8 ah = *(const short8*)(wa);
            short8 am = *(const short8*)(wa + WM_PLANE);
            short8 al = *(const short8*)(wa + 2 * WM_PLANE);
            const unsigned short* bb = Bh + lr * 296 + kk + lg * 8;
            short8 bh = *(const short8*)(bb);
            short8 bm = *(const short8*)(bb + 4736);
            short8 bl = *(const short8*)(bb + 9472);
            acc1 = __builtin_amdgcn_mfma_f32_16x16x32_bf16(ah, bh, acc1, 0, 0, 0);
            acc1 = __builtin_amdgcn_mfma_f32_16x16x32_bf16(ah, bm, acc1, 0, 0, 0);
            acc1 = __builtin_amdgcn_mfma_f32_16x16x32_bf16(am, bh, acc1, 0, 0, 0);
            acc1 = __builtin_amdgcn_mfma_f32_16x16x32_bf16(ah, bl, acc1, 0, 0, 0);
            acc1 = __builtin_amdgcn_mfma_f32_16x16x32_bf16(am, bm, acc1, 0, 0, 0);
            acc1 = __builtin_amdgcn_mfma_f32_16x16x32_bf16(al, bh, acc1, 0, 0, 0);
        }
        __syncthreads();
    }
    *(f32x4*)(s_part + (wv * 64 + lane) * 4) = acc1;
    __syncthreads();

    // combine K-split partials, apply bias/sigmoid
    #pragma unroll
    for (int half = 0; half < 2; ++half) {
        int idx = t + half * 256;
        int reg = idx & 3, ln = (idx >> 2) & 63, tl = idx >> 8;
        int row = (ln >> 4) * 4 + reg, oc = tl * 16 + row, pix = ln & 15;
        if (oc < 30) {
            float v = s_part[(tl * 64 + ln) * 4 + reg] + s_part[((tl + 2) * 64 + ln) * 4 + reg];
            if (oc < 18)      s_off[pix * 18 + oc] = v + b_p[oc];
            else if (oc < 21) s_adb[pix * 3 + (oc - 18)] = 1.f - 1.f / (1.f + expf(-v));
            else              s_mraw[pix * 9 + (oc - 21)] = v;
        }
    }
    __syncthreads();

    // ---- Phase 2: sampling corners + premultiplied bilinear*modulation weights ----
    if (t < PIX * 9) {
        int pix = t / 9; int n = t % 9;
        int ki = n / 3, kj = n % 3;
        float adb  = s_adb[pix * 3 + kj];
        float offx = s_off[pix * 18 + n];
        float offy = s_off[pix * 18 + 9 + n];
        float pnx = (float)(ki - 1), pny = (float)(kj - 1);
        float px = (float)(i + 1)        + pnx + offx + 2.f * adb * pnx;
        float py = (float)(j0 + pix + 1) + pny + offy + 2.f * adb * pny;

        float flx = floorf(px), fly = floorf(py);
        int ix0 = (int)fminf(fmaxf(flx,       0.f), 129.f);
        int ix1 = (int)fminf(fmaxf(flx + 1.f, 0.f), 129.f);
        int iy0 = (int)fminf(fmaxf(fly,       0.f), 129.f);
        int iy1 = (int)fminf(fmaxf(fly + 1.f, 0.f), 129.f);

        float ptx = (px < 1.f || px > 128.f) ? flx : px;
        float pty = (py < 1.f || py > 128.f) ? fly : py;
        ptx = fminf(fmaxf(ptx, 0.f), 129.f);
        pty = fminf(fmaxf(pty, 0.f), 129.f);

        float wxl = 1.f + (float)ix0 - ptx;
        float wxr = 1.f - ((float)ix1 - ptx);
        float wyl = 1.f + (float)iy0 - pty;
        float wyr = 1.f - ((float)iy1 - pty);

        float mraw = s_mraw[pix * 9 + n];
        float mm = (1.f / (1.f + expf(-mraw))) * (adb - 0.5f) * 4.f;

        int base = (pix * 9 + n) * 4;
        s_g[base + 0] = wxl * wyl * mm;
        s_g[base + 1] = wxr * wyr * mm;
        s_g[base + 2] = wxl * wyr * mm;
        s_g[base + 3] = wxr * wyl * mm;
        s_idxp[pix * 9 + n] = ix0 | (ix1 << 8) | (iy0 << 16) | (iy1 << 24);
    }
    __syncthreads();

    // ---- Phase 3: bilinear gathers from xT (NHWC bf16) -> s_valb[pix][n*64+ci] ----
    const unsigned short* xb = xT + (size_t)b * (128 * 128 * 64);
    for (int it = 0; it < 9; ++it) {
        int task = t + it * 256;                 // 2304 = 16 cig * 9 n * 16 pix
        int cig = task & 15, rest = task >> 4;
        int n = rest % 9, pix = rest / 9;
        int pk = s_idxp[pix * 9 + n];
        int ix0 = pk & 255, ix1 = (pk >> 8) & 255;
        int iy0 = (pk >> 16) & 255, iy1 = (pk >> 24) & 255;
        f32x4 g = *(const f32x4*)(s_g + (pix * 9 + n) * 4);
        int rx0 = ix0 - 1, ry0 = iy0 - 1, rx1 = ix1 - 1, ry1 = iy1 - 1;
        float a0 = 0.f, a1 = 0.f, a2 = 0.f, a3 = 0.f;
        #define CORNER(RX, RY, G) do { \
            if ((unsigned)(RX) < 128u && (unsigned)(RY) < 128u) { \
                uint2 u = *(const uint2*)(xb + ((RX) * 128 + (RY)) * 64 + cig * 4); \
                a0 += (G) * bflo2f(u.x); a1 += (G) * bfhi2f(u.x); \
                a2 += (G) * bflo2f(u.y); a3 += (G) * bfhi2f(u.y); \
            } } while (0)
        CORNER(rx0, ry0, g[0]);
        CORNER(rx1, ry1, g[1]);
        CORNER(rx0, ry1, g[2]);
        CORNER(rx1, ry0, g[3]);
        #undef CORNER
        unsigned p0 = f2bf_u(a0) | (f2bf_u(a1) << 16);
        unsigned p1 = f2bf_u(a2) | (f2bf_u(a3) << 16);
        *(uint2*)(s_valb + pix * 584 + n * 64 + cig * 4) = make_uint2(p0, p1);
    }
    __syncthreads();

    // ---- Phase 4: MFMA contraction out[co][pix] ----
    {
        const unsigned short* wa = wc16 + (wv * 16 + lr) * 576 + lg * 8;
        const unsigned short* vb = s_valb + lr * 584 + lg * 8;
        f32x4 acc = {0.f, 0.f, 0.f, 0.f};
        #pragma unroll 6
        for (int kk = 0; kk < 18; ++kk) {
            short8 a  = *(const short8*)(wa + kk * 32);
            short8 bf = *(const short8*)(vb + kk * 32);
            acc = __builtin_amdgcn_mfma_f32_16x16x32_bf16(a, bf, acc, 0, 0, 0);
        }
        #pragma unroll
        for (int r = 0; r < 4; ++r)
            out[(((size_t)b * 64 + wv * 16 + lg * 4 + r) * 128 + i) * 128 + j0 + lr] = acc[r];
    }
}

extern "C" void kernel_launch(void* const* d_in, const int* in_sizes, int n_in,
                              void* d_out, int out_size, void* d_ws, size_t ws_size,
                              hipStream_t stream) {
    const float* x      = (const float*)d_in[0];
    const float* w_p    = (const float*)d_in[1];
    const float* b_p    = (const float*)d_in[2];
    const float* w_m    = (const float*)d_in[3];
    const float* w_ad   = (const float*)d_in[4];
    const float* w_conv = (const float*)d_in[5];
    float* outp = (float*)d_out;
    unsigned short* ws = (unsigned short*)d_ws;

    prep_kernel<<<364, 256, 0, stream>>>(x, w_p, w_m, w_ad, w_conv, ws);
    dim3 grid(BATCH * H * (W / PIX));
    deform_kernel<<<grid, 256, 0, stream>>>(x, b_p, ws, outp);
}